// Round 1
// baseline (598.778 us; speedup 1.0000x reference)
//
#include <hip/hip_runtime.h>
#include <hip/hip_bf16.h>
#include <cstdint>

typedef __attribute__((ext_vector_type(8))) short short8;
typedef __attribute__((ext_vector_type(4))) float f32x4;
typedef __attribute__((ext_vector_type(8))) unsigned short ushort8;

#define B_ 16
#define T_ 2048
#define D_ 1024
#define M_ (B_*T_)   // 32768
#define NC 32        // scan chunks
#define CL 64        // chunk length = T_/NC

static __device__ __forceinline__ float bf2f(unsigned short u) {
  unsigned int x = ((unsigned int)u) << 16;
  return __builtin_bit_cast(float, x);
}
static __device__ __forceinline__ unsigned short f2bf(float f) {
  unsigned int x = __builtin_bit_cast(unsigned int, f);
  unsigned int r = x + 0x7fffu + ((x >> 16) & 1u);
  return (unsigned short)(r >> 16);
}
static __device__ __forceinline__ float sigmoidf(float v) {
  return 1.f / (1.f + __expf(-v));
}

typedef const __attribute__((address_space(1))) unsigned int* gas1_t;
typedef __attribute__((address_space(3))) unsigned int* las3_t;
static __device__ __forceinline__ void async_copy16(const void* g, void* l) {
  __builtin_amdgcn_global_load_lds((gas1_t)g, (las3_t)l, 16, 0, 0);
}

// ---------------- fp32 -> bf16 convert (x8 vectorized) ----------------
__global__ void cvt_f32_bf16(const float* __restrict__ in,
                             unsigned short* __restrict__ out, long n8) {
  long i = (long)blockIdx.x * blockDim.x + threadIdx.x;
  long stride = (long)gridDim.x * blockDim.x;
  for (; i < n8; i += stride) {
    const float4* p = (const float4*)(in + i * 8);
    float4 a = p[0], b = p[1];
    ushort8 o;
    o[0] = f2bf(a.x); o[1] = f2bf(a.y); o[2] = f2bf(a.z); o[3] = f2bf(a.w);
    o[4] = f2bf(b.x); o[5] = f2bf(b.y); o[6] = f2bf(b.z); o[7] = f2bf(b.w);
    *(ushort8*)(out + i * 8) = o;
  }
}

// ---------------- bf16 GEMM: C[M,N] = A[M,K(lda)] * Bw[N,K]^T + bias ----------------
// EPI 0: +bias, store bf16 ; EPI 1: sigmoid(+bias), store bf16 ; EPI 2: +bias, store fp32
template<int EPI>
__global__ __launch_bounds__(256) void gemm_bt(
    const unsigned short* __restrict__ A, long lda,
    const unsigned short* __restrict__ Bw,
    const float* __restrict__ bias,
    void* __restrict__ Cout, long ldc,
    int M, int N, int K)
{
  __shared__ __align__(16) unsigned short sA[128 * 32];
  __shared__ __align__(16) unsigned short sB[128 * 32];
  const int tid  = threadIdx.x;
  const int wave = tid >> 6;
  const int lane = tid & 63;
  const int wm = wave >> 1;     // wave row (0..1) -> 64 rows
  const int wn = wave & 1;      // wave col (0..1) -> 64 cols
  const long m0 = (long)blockIdx.y * 128;
  const long n0 = (long)blockIdx.x * 128;

  f32x4 acc[4][4] = {};

  for (int kk = 0; kk < K; kk += 32) {
#pragma unroll
    for (int i = 0; i < 2; ++i) {
      // LDS tile layout: row-major [128][32] bf16 (64 B per row)
      int eb  = wave * 2048 + i * 1024 + lane * 16;  // byte offset in tile
      int row = eb >> 6;
      int kb  = eb & 63;
      const char* gA = (const char*)(A + (m0 + row) * lda) + (long)kk * 2 + kb;
      async_copy16(gA, (char*)sA + wave * 2048 + i * 1024);
      const char* gB = (const char*)(Bw + (n0 + row) * (long)K) + (long)kk * 2 + kb;
      async_copy16(gB, (char*)sB + wave * 2048 + i * 1024);
    }
    __syncthreads();   // drain global_load_lds, tile visible

    const int lr = lane & 15;
    const int kq = lane >> 4;
    short8 af[4], bf[4];
#pragma unroll
    for (int m = 0; m < 4; ++m)
      af[m] = *(const short8*)&sA[(wm * 64 + m * 16 + lr) * 32 + kq * 8];
#pragma unroll
    for (int n = 0; n < 4; ++n)
      bf[n] = *(const short8*)&sB[(wn * 64 + n * 16 + lr) * 32 + kq * 8];
#pragma unroll
    for (int m = 0; m < 4; ++m)
#pragma unroll
      for (int n = 0; n < 4; ++n)
        acc[m][n] = __builtin_amdgcn_mfma_f32_16x16x32_bf16(af[m], bf[n], acc[m][n], 0, 0, 0);

    __syncthreads();   // all reads done before next-overwrite
  }

  // epilogue: C/D layout col=lane&15, row=(lane>>4)*4+reg
  const int lr = lane & 15;
  const int rq = lane >> 4;
#pragma unroll
  for (int m = 0; m < 4; ++m) {
    long row0 = m0 + wm * 64 + m * 16 + rq * 4;
#pragma unroll
    for (int n = 0; n < 4; ++n) {
      long col = n0 + wn * 64 + n * 16 + lr;
      float bv = bias[col];
#pragma unroll
      for (int r = 0; r < 4; ++r) {
        float v = acc[m][n][r] + bv;
        if (EPI == 1) v = sigmoidf(v);
        if (EPI == 2) {
          ((float*)Cout)[(row0 + r) * ldc + col] = v;
        } else {
          ((unsigned short*)Cout)[(row0 + r) * ldc + col] = f2bf(v);
        }
      }
    }
  }
}

// ---------------- scan pass A: per-chunk decay product + local h ----------------
// thread handles 8 consecutive d. idx = (((b*NC)+c)*128 + d8)
__global__ void scan_passA(const unsigned short* __restrict__ dtb,   // [M,D] bf16
                           const unsigned short* __restrict__ xz,    // [M,2D] bf16
                           float* __restrict__ P, float* __restrict__ Hl)
{
  int idx = blockIdx.x * blockDim.x + threadIdx.x;   // 0 .. 65535
  int d8 = idx & 127;
  int c  = (idx >> 7) & 31;
  int b  = idx >> 12;
  int d0 = d8 * 8;
  long mbase = (long)b * T_ + (long)c * CL;
  float h[8] = {0,0,0,0,0,0,0,0};
  float p[8] = {1,1,1,1,1,1,1,1};
  for (int t = 0; t < CL; ++t) {
    long m = mbase + t;
    ushort8 dv = *(const ushort8*)(dtb + m * D_ + d0);
    ushort8 xv = *(const ushort8*)(xz + m * (2 * D_) + d0);
#pragma unroll
    for (int j = 0; j < 8; ++j) {
      float dt = bf2f(dv[j]);
      float xp = bf2f(xv[j]);
      float om = 1.f - dt;
      h[j] = om * h[j] + dt * xp;
      p[j] *= om;
    }
  }
  long pb = ((long)(b * NC + c)) * D_ + d0;
#pragma unroll
  for (int j = 0; j < 8; ++j) { P[pb + j] = p[j]; Hl[pb + j] = h[j]; }
}

// ---------------- scan pass C: fold chunk summaries + replay, fuse sigmoid(gate) ----------------
__global__ void scan_passC(unsigned short* dts,                      // in: dt, out: s (in-place)
                           const unsigned short* __restrict__ xz,    // [M,2D]
                           const float* __restrict__ h0,             // [B,D]
                           const float* __restrict__ P,
                           const float* __restrict__ Hl)
{
  int idx = blockIdx.x * blockDim.x + threadIdx.x;
  int d8 = idx & 127;
  int c  = (idx >> 7) & 31;
  int b  = idx >> 12;
  int d0 = d8 * 8;
  long mbase = (long)b * T_ + (long)c * CL;

  float h[8];
#pragma unroll
  for (int j = 0; j < 8; ++j) h[j] = h0[(long)b * D_ + d0 + j];

  // fold previous chunks' (P, Hl): h = Hl + P*h  (L2-resident, 4 MB arrays)
  for (int jc = 0; jc < c; ++jc) {
    long pb = ((long)(b * NC + jc)) * D_ + d0;
    float pj[8], hj[8];
    *(f32x4*)&pj[0] = *(const f32x4*)(P + pb);
    *(f32x4*)&pj[4] = *(const f32x4*)(P + pb + 4);
    *(f32x4*)&hj[0] = *(const f32x4*)(Hl + pb);
    *(f32x4*)&hj[4] = *(const f32x4*)(Hl + pb + 4);
#pragma unroll
    for (int j = 0; j < 8; ++j) h[j] = hj[j] + pj[j] * h[j];
  }

  for (int t = 0; t < CL; ++t) {
    long m = mbase + t;
    ushort8 dv = *(const ushort8*)(dts + m * D_ + d0);
    ushort8 xv = *(const ushort8*)(xz + m * (2 * D_) + d0);
    ushort8 gv = *(const ushort8*)(xz + m * (2 * D_) + D_ + d0);
    ushort8 ov;
#pragma unroll
    for (int j = 0; j < 8; ++j) {
      float dt = bf2f(dv[j]);
      float xp = bf2f(xv[j]);
      h[j] = (1.f - dt) * h[j] + dt * xp;
      float g = bf2f(gv[j]);
      ov[j] = f2bf(h[j] * sigmoidf(g));
    }
    *(ushort8*)(dts + m * D_ + d0) = ov;   // overwrite dt with s (same element, read first)
  }
}

// ---------------- launch ----------------
extern "C" void kernel_launch(void* const* d_in, const int* in_sizes, int n_in,
                              void* d_out, int out_size, void* d_ws, size_t ws_size,
                              hipStream_t stream) {
  const float* x     = (const float*)d_in[0];
  const float* h0    = (const float*)d_in[1];
  const float* W_in  = (const float*)d_in[2];
  const float* b_in  = (const float*)d_in[3];
  const float* W_dt  = (const float*)d_in[4];
  const float* b_dt  = (const float*)d_in[5];
  const float* W_out = (const float*)d_in[6];
  const float* b_out = (const float*)d_in[7];
  float* out = (float*)d_out;

  // workspace layout (bytes)
  char* ws = (char*)d_ws;
  const size_t OFF_XB    = 0;                     // x bf16        [M,D]    64 MiB
  const size_t OFF_WIN   = 67108864;              // W_in bf16     [2D,D]    4 MiB
  const size_t OFF_WDT   = 71303168;              // W_dt bf16     [D,D]     2 MiB
  const size_t OFF_WOUT  = 73400320;              // W_out bf16    [D,D]     2 MiB
  const size_t OFF_XZ    = 75497472;              // xz bf16       [M,2D]  128 MiB
  const size_t OFF_DTS   = 209715200;             // dt/s bf16     [M,D]    64 MiB
  const size_t OFF_P     = 276824064;             // P fp32        [B,NC,D]  2 MiB
  const size_t OFF_HL    = 278921216;             // Hl fp32       [B,NC,D]  2 MiB
  const size_t NEEDED    = 281018368;
  if (ws_size < NEEDED) return;  // loud failure (output stays poisoned)

  unsigned short* xb    = (unsigned short*)(ws + OFF_XB);
  unsigned short* wbin  = (unsigned short*)(ws + OFF_WIN);
  unsigned short* wbdt  = (unsigned short*)(ws + OFF_WDT);
  unsigned short* wbout = (unsigned short*)(ws + OFF_WOUT);
  unsigned short* xz    = (unsigned short*)(ws + OFF_XZ);
  unsigned short* dts   = (unsigned short*)(ws + OFF_DTS);
  float* P  = (float*)(ws + OFF_P);
  float* Hl = (float*)(ws + OFF_HL);

  cvt_f32_bf16<<<2048, 256, 0, stream>>>(x, xb, (long)M_ * D_ / 8);
  cvt_f32_bf16<<<512, 256, 0, stream>>>(W_in, wbin, (long)2 * D_ * D_ / 8);
  cvt_f32_bf16<<<256, 256, 0, stream>>>(W_dt, wbdt, (long)D_ * D_ / 8);
  cvt_f32_bf16<<<256, 256, 0, stream>>>(W_out, wbout, (long)D_ * D_ / 8);

  // xz = x @ W_in^T + b_in            (bf16 out, [M, 2D])
  gemm_bt<0><<<dim3(2 * D_ / 128, M_ / 128), 256, 0, stream>>>(
      xb, D_, wbin, b_in, xz, 2 * D_, M_, 2 * D_, D_);
  // dt = sigmoid(x_part @ W_dt^T + b_dt)   (bf16 out, [M, D]); x_part = xz[:, :D]
  gemm_bt<1><<<dim3(D_ / 128, M_ / 128), 256, 0, stream>>>(
      xz, 2 * D_, wbdt, b_dt, dts, D_, M_, D_, D_);
  // chunked scan
  scan_passA<<<256, 256, 0, stream>>>(dts, xz, P, Hl);
  scan_passC<<<256, 256, 0, stream>>>(dts, xz, h0, P, Hl);
  // y = s @ W_out^T + b_out           (fp32 out)
  gemm_bt<2><<<dim3(D_ / 128, M_ / 128), 256, 0, stream>>>(
      dts, D_, wbout, b_out, out, D_, M_, D_, D_);
}

// Round 2
// 464.670 us; speedup vs baseline: 1.2886x; 1.2886x over previous
//
#include <hip/hip_runtime.h>
#include <hip/hip_bf16.h>
#include <cstdint>

typedef __attribute__((ext_vector_type(8))) short short8;
typedef __attribute__((ext_vector_type(4))) float f32x4;
typedef __attribute__((ext_vector_type(8))) unsigned short ushort8;

#define B_ 16
#define T_ 2048
#define D_ 1024
#define M_ (B_*T_)   // 32768
#define NC 32        // scan chunks
#define CL 64        // chunk length = T_/NC

static __device__ __forceinline__ float bf2f(unsigned short u) {
  unsigned int x = ((unsigned int)u) << 16;
  return __builtin_bit_cast(float, x);
}
static __device__ __forceinline__ unsigned short f2bf(float f) {
  unsigned int x = __builtin_bit_cast(unsigned int, f);
  unsigned int r = x + 0x7fffu + ((x >> 16) & 1u);
  return (unsigned short)(r >> 16);
}
static __device__ __forceinline__ float sigmoidf(float v) {
  return 1.f / (1.f + __expf(-v));
}

typedef const __attribute__((address_space(1))) unsigned int* gas1_t;
typedef __attribute__((address_space(3))) unsigned int* las3_t;
static __device__ __forceinline__ void async_copy16(const void* g, void* l) {
  __builtin_amdgcn_global_load_lds((gas1_t)g, (las3_t)l, 16, 0, 0);
}

#define VMCNT4 asm volatile("s_waitcnt vmcnt(4)" ::: "memory")
#define VMCNT2 asm volatile("s_waitcnt vmcnt(2)" ::: "memory")
#define VMCNT0 asm volatile("s_waitcnt vmcnt(0)" ::: "memory")
#define SBAR   __builtin_amdgcn_s_barrier()
#define SCHED0 __builtin_amdgcn_sched_barrier(0)

// ---------------- fp32 -> bf16 convert (x8 vectorized) ----------------
__global__ void cvt_f32_bf16(const float* __restrict__ in,
                             unsigned short* __restrict__ out, long n8) {
  long i = (long)blockIdx.x * blockDim.x + threadIdx.x;
  long stride = (long)gridDim.x * blockDim.x;
  for (; i < n8; i += stride) {
    const float4* p = (const float4*)(in + i * 8);
    float4 a = p[0], b = p[1];
    ushort8 o;
    o[0] = f2bf(a.x); o[1] = f2bf(a.y); o[2] = f2bf(a.z); o[3] = f2bf(a.w);
    o[4] = f2bf(b.x); o[5] = f2bf(b.y); o[6] = f2bf(b.z); o[7] = f2bf(b.w);
    *(ushort8*)(out + i * 8) = o;
  }
}

// ---------------- 256x256 8-phase bf16 GEMM: C[M,N] = A[M,K] * Bw[N,K]^T + bias ----
// K = 1024 fixed (KT=16 tiles of BK=64). 8 waves (2M x 4N), per-wave out 128x64.
// LDS 128 KB: A[2buf][2half][128r][64k], B likewise, at byte ^= ((row&7)<<4) swizzle.
//   A half h, LDS-local row lr -> global tile row (lr>>6)*128 + h*64 + (lr&63)
//   B half h, LDS-local row lr -> global tile n   (lr>>5)*64  + h*32 + (lr&31)
// (phase-consumption order: phase(mh,nh) reads exactly A-half mh + B-half nh)
// Schedule per K-tile t (phases P0..P3 = quadrants (0,0),(0,1),(1,0),(1,1)):
//   P0 issues A0(t+1), P1 B0(t+1), P2 B1(t+1), P3 A1(t+1)  [2 loads each]
// Needs: P0 reads A0,B0(t); P1 reads B1(t); P2 reads A1(t).
// Counted waits (before closing barrier): end-P0 vmcnt(4) [B1(t) done],
//   end-P1 vmcnt(4) [A1(t) done], end-P3 vmcnt(4) [A0,B0(t+1) done].
// Last tile (no issues): end-P0 vmcnt(2), end-P1 vmcnt(0).
// EPI 0: +bias->bf16 ; EPI 1: sigmoid(+bias)->bf16 ; EPI 2: +bias->fp32
template<int EPI>
__global__ __launch_bounds__(512, 2) void gemm256(
    const unsigned short* __restrict__ A, long lda,
    const unsigned short* __restrict__ Bw,
    const float* __restrict__ bias,
    void* __restrict__ Cout, long ldc,
    int nbx)
{
  constexpr int KT = 16;
  __shared__ __align__(16) unsigned short lds[65536];  // 128 KiB

  const int tid = threadIdx.x;
  const int l  = tid & 63, w = tid >> 6;
  const int wm = w >> 2, wn = w & 3;
  const int fr = l & 15, g = l >> 4;
  const int t8 = tid >> 3;                       // = w*8 + l/8
  const int c8x = ((l & 7) ^ (l >> 3)) << 4;     // staging source XOR (bytes)
  const int s0 = ((g ^ (fr & 7)) << 4);          // ds_read swizzle, kk=0
  const int s1 = s0 ^ 0x40;                      // kk=1 (c8 bit2 -> byte bit6)
  const int tB = (w >> 2) * 64 + (w & 3) * 8 + (l >> 3);

  // XCD-aware bijective swizzle (nwg % 8 == 0 for all our grids)
  const int nwg = gridDim.x;
  const int cpx = nwg >> 3;
  const int bid = blockIdx.x;
  const int swz = (bid & 7) * cpx + (bid >> 3);
  const long m0 = (long)(swz / nbx) * 256;
  const long n0 = (long)(swz % nbx) * 256;

  const char* Ab = (const char*)A;
  const char* Bb = (const char*)Bw;
  const long ldab = lda * 2;
  char* LB = (char*)lds;

  auto stA = [&](int kt, int h, int nb) {
    char* lb = LB + nb * 32768 + h * 16384 + w * 1024;
    long col = (long)kt * 128 + c8x;
    async_copy16(Ab + (m0 + h * 64 + t8) * ldab + col, lb);
    async_copy16(Ab + (m0 + 128 + h * 64 + t8) * ldab + col, lb + 8192);
  };
  auto stB = [&](int kt, int h, int nb) {
    char* lb = LB + 65536 + nb * 32768 + h * 16384 + w * 1024;
    long col = (long)kt * 128 + c8x;
    async_copy16(Bb + (n0 + tB + h * 32) * 2048 + col, lb);
    async_copy16(Bb + (n0 + tB + 128 + h * 32) * 2048 + col, lb + 8192);
  };

  f32x4 acc[8][4] = {};

  // prologue: tile 0 half-tiles in steady-state issue order A0,B0,B1,A1
  stA(0, 0, 0); stB(0, 0, 0); stB(0, 1, 0); stA(0, 1, 0);
  VMCNT4; SCHED0; SBAR;

#define PH(mh, nh, STG, VMW) do {                                              \
    const char* pa0 = LB + cur * 32768 + (mh) * 16384 + wm * 8192 + fr * 128 + s0; \
    const char* pa1 = LB + cur * 32768 + (mh) * 16384 + wm * 8192 + fr * 128 + s1; \
    const char* pb0 = LB + 65536 + cur * 32768 + (nh) * 16384 + wn * 4096 + fr * 128 + s0; \
    const char* pb1 = LB + 65536 + cur * 32768 + (nh) * 16384 + wn * 4096 + fr * 128 + s1; \
    short8 af[4][2]; short8 bf[2][2];                                          \
    _Pragma("unroll") for (int mi = 0; mi < 4; ++mi) {                         \
      af[mi][0] = *(const short8*)(pa0 + mi * 2048);                           \
      af[mi][1] = *(const short8*)(pa1 + mi * 2048); }                         \
    _Pragma("unroll") for (int ni = 0; ni < 2; ++ni) {                         \
      bf[ni][0] = *(const short8*)(pb0 + ni * 2048);                           \
      bf[ni][1] = *(const short8*)(pb1 + ni * 2048); }                         \
    STG;                                                                       \
    SCHED0; SBAR;                                                              \
    __builtin_amdgcn_s_setprio(1);                                             \
    _Pragma("unroll") for (int mi = 0; mi < 4; ++mi)                           \
    _Pragma("unroll") for (int ni = 0; ni < 2; ++ni) {                         \
      acc[(mh)*4+mi][(nh)*2+ni] = __builtin_amdgcn_mfma_f32_16x16x32_bf16(     \
          af[mi][0], bf[ni][0], acc[(mh)*4+mi][(nh)*2+ni], 0, 0, 0);           \
      acc[(mh)*4+mi][(nh)*2+ni] = __builtin_amdgcn_mfma_f32_16x16x32_bf16(     \
          af[mi][1], bf[ni][1], acc[(mh)*4+mi][(nh)*2+ni], 0, 0, 0); }         \
    __builtin_amdgcn_s_setprio(0);                                             \
    VMW;                                                                       \
    SCHED0; SBAR; SCHED0;                                                      \
  } while (0)

#pragma unroll 2
  for (int t = 0; t < KT; ++t) {
    const int cur = t & 1, nxt = cur ^ 1;
    const bool notlast = (t + 1 < KT);
    PH(0, 0, if (notlast) stA(t + 1, 0, nxt), { if (notlast) { VMCNT4; } else { VMCNT2; } });
    PH(0, 1, if (notlast) stB(t + 1, 0, nxt), { if (notlast) { VMCNT4; } else { VMCNT0; } });
    PH(1, 0, if (notlast) stB(t + 1, 1, nxt), {});
    PH(1, 1, if (notlast) stA(t + 1, 1, nxt), { if (notlast) { VMCNT4; } });
  }
#undef PH

  // epilogue: C/D layout col=lane&15, row=(lane>>4)*4+r
  const int rq = l >> 4;
#pragma unroll
  for (int mi = 0; mi < 8; ++mi) {
    long row0 = m0 + wm * 128 + mi * 16 + rq * 4;
#pragma unroll
    for (int ni = 0; ni < 4; ++ni) {
      long col = n0 + wn * 64 + ni * 16 + fr;
      float bv = bias[col];
#pragma unroll
      for (int r = 0; r < 4; ++r) {
        float v = acc[mi][ni][r] + bv;
        if (EPI == 1) v = sigmoidf(v);
        if (EPI == 2) {
          ((float*)Cout)[(row0 + r) * ldc + col] = v;
        } else {
          ((unsigned short*)Cout)[(row0 + r) * ldc + col] = f2bf(v);
        }
      }
    }
  }
}

// ---------------- scan pass A: per-chunk decay product + local h ----------------
__global__ void scan_passA(const unsigned short* __restrict__ dtb,   // [M,D] bf16
                           const unsigned short* __restrict__ xz,    // [M,2D] bf16
                           float* __restrict__ P, float* __restrict__ Hl)
{
  int idx = blockIdx.x * blockDim.x + threadIdx.x;   // 0 .. 65535
  int d8 = idx & 127;
  int c  = (idx >> 7) & 31;
  int b  = idx >> 12;
  int d0 = d8 * 8;
  long mbase = (long)b * T_ + (long)c * CL;
  float h[8] = {0,0,0,0,0,0,0,0};
  float p[8] = {1,1,1,1,1,1,1,1};
  for (int t = 0; t < CL; ++t) {
    long m = mbase + t;
    ushort8 dv = *(const ushort8*)(dtb + m * D_ + d0);
    ushort8 xv = *(const ushort8*)(xz + m * (2 * D_) + d0);
#pragma unroll
    for (int j = 0; j < 8; ++j) {
      float dt = bf2f(dv[j]);
      float xp = bf2f(xv[j]);
      float om = 1.f - dt;
      h[j] = om * h[j] + dt * xp;
      p[j] *= om;
    }
  }
  long pb = ((long)(b * NC + c)) * D_ + d0;
#pragma unroll
  for (int j = 0; j < 8; ++j) { P[pb + j] = p[j]; Hl[pb + j] = h[j]; }
}

// ---------------- scan pass C: fold chunk summaries + replay, fuse sigmoid(gate) ----
__global__ void scan_passC(unsigned short* dts,                      // in: dt, out: s
                           const unsigned short* __restrict__ xz,    // [M,2D]
                           const float* __restrict__ h0,             // [B,D]
                           const float* __restrict__ P,
                           const float* __restrict__ Hl)
{
  int idx = blockIdx.x * blockDim.x + threadIdx.x;
  int d8 = idx & 127;
  int c  = (idx >> 7) & 31;
  int b  = idx >> 12;
  int d0 = d8 * 8;
  long mbase = (long)b * T_ + (long)c * CL;

  float h[8];
#pragma unroll
  for (int j = 0; j < 8; ++j) h[j] = h0[(long)b * D_ + d0 + j];

  for (int jc = 0; jc < c; ++jc) {
    long pb = ((long)(b * NC + jc)) * D_ + d0;
    float pj[8], hj[8];
    *(f32x4*)&pj[0] = *(const f32x4*)(P + pb);
    *(f32x4*)&pj[4] = *(const f32x4*)(P + pb + 4);
    *(f32x4*)&hj[0] = *(const f32x4*)(Hl + pb);
    *(f32x4*)&hj[4] = *(const f32x4*)(Hl + pb + 4);
#pragma unroll
    for (int j = 0; j < 8; ++j) h[j] = hj[j] + pj[j] * h[j];
  }

  for (int t = 0; t < CL; ++t) {
    long m = mbase + t;
    ushort8 dv = *(const ushort8*)(dts + m * D_ + d0);
    ushort8 xv = *(const ushort8*)(xz + m * (2 * D_) + d0);
    ushort8 gv = *(const ushort8*)(xz + m * (2 * D_) + D_ + d0);
    ushort8 ov;
#pragma unroll
    for (int j = 0; j < 8; ++j) {
      float dt = bf2f(dv[j]);
      float xp = bf2f(xv[j]);
      h[j] = (1.f - dt) * h[j] + dt * xp;
      float gt = bf2f(gv[j]);
      ov[j] = f2bf(h[j] * sigmoidf(gt));
    }
    *(ushort8*)(dts + m * D_ + d0) = ov;
  }
}

// ---------------- launch ----------------
extern "C" void kernel_launch(void* const* d_in, const int* in_sizes, int n_in,
                              void* d_out, int out_size, void* d_ws, size_t ws_size,
                              hipStream_t stream) {
  const float* x     = (const float*)d_in[0];
  const float* h0    = (const float*)d_in[1];
  const float* W_in  = (const float*)d_in[2];
  const float* b_in  = (const float*)d_in[3];
  const float* W_dt  = (const float*)d_in[4];
  const float* b_dt  = (const float*)d_in[5];
  const float* W_out = (const float*)d_in[6];
  const float* b_out = (const float*)d_in[7];
  float* out = (float*)d_out;

  char* ws = (char*)d_ws;
  const size_t OFF_XB    = 0;                     // x bf16        [M,D]    64 MiB
  const size_t OFF_WIN   = 67108864;              // W_in bf16     [2D,D]    4 MiB
  const size_t OFF_WDT   = 71303168;              // W_dt bf16     [D,D]     2 MiB
  const size_t OFF_WOUT  = 73400320;              // W_out bf16    [D,D]     2 MiB
  const size_t OFF_XZ    = 75497472;              // xz bf16       [M,2D]  128 MiB
  const size_t OFF_DTS   = 209715200;             // dt/s bf16     [M,D]    64 MiB
  const size_t OFF_P     = 276824064;             // P fp32        [B,NC,D]  2 MiB
  const size_t OFF_HL    = 278921216;             // Hl fp32       [B,NC,D]  2 MiB
  const size_t NEEDED    = 281018368;
  if (ws_size < NEEDED) return;

  unsigned short* xb    = (unsigned short*)(ws + OFF_XB);
  unsigned short* wbin  = (unsigned short*)(ws + OFF_WIN);
  unsigned short* wbdt  = (unsigned short*)(ws + OFF_WDT);
  unsigned short* wbout = (unsigned short*)(ws + OFF_WOUT);
  unsigned short* xz    = (unsigned short*)(ws + OFF_XZ);
  unsigned short* dts   = (unsigned short*)(ws + OFF_DTS);
  float* P  = (float*)(ws + OFF_P);
  float* Hl = (float*)(ws + OFF_HL);

  cvt_f32_bf16<<<2048, 256, 0, stream>>>(x, xb, (long)M_ * D_ / 8);
  cvt_f32_bf16<<<512, 256, 0, stream>>>(W_in, wbin, (long)2 * D_ * D_ / 8);
  cvt_f32_bf16<<<256, 256, 0, stream>>>(W_dt, wbdt, (long)D_ * D_ / 8);
  cvt_f32_bf16<<<256, 256, 0, stream>>>(W_out, wbout, (long)D_ * D_ / 8);

  // xz = x @ W_in^T + b_in            (bf16 out, [M, 2D])
  gemm256<0><<<(M_/256)*(2*D_/256), 512, 0, stream>>>(xb, D_, wbin, b_in, xz, 2*D_, 2*D_/256);
  // dt = sigmoid(x_part @ W_dt^T + b_dt)   (bf16 out, [M, D]); x_part = xz[:, :D]
  gemm256<1><<<(M_/256)*(D_/256), 512, 0, stream>>>(xz, 2*D_, wbdt, b_dt, dts, D_, D_/256);
  // chunked scan
  scan_passA<<<256, 256, 0, stream>>>(dts, xz, P, Hl);
  scan_passC<<<256, 256, 0, stream>>>(dts, xz, h0, P, Hl);
  // y = s @ W_out^T + b_out           (fp32 out)
  gemm256<2><<<(M_/256)*(D_/256), 512, 0, stream>>>(dts, D_, wbout, b_out, out, D_, D_/256);
}

// Round 3
// 446.739 us; speedup vs baseline: 1.3403x; 1.0401x over previous
//
#include <hip/hip_runtime.h>
#include <hip/hip_bf16.h>
#include <cstdint>

typedef __attribute__((ext_vector_type(8))) short short8;
typedef __attribute__((ext_vector_type(4))) float f32x4;
typedef __attribute__((ext_vector_type(8))) unsigned short ushort8;

#define B_ 16
#define T_ 2048
#define D_ 1024
#define M_ (B_*T_)   // 32768
#define NC 32        // scan chunks
#define CL 64        // chunk length = T_/NC

static __device__ __forceinline__ float bf2f(unsigned short u) {
  unsigned int x = ((unsigned int)u) << 16;
  return __builtin_bit_cast(float, x);
}
static __device__ __forceinline__ unsigned short f2bf(float f) {
  unsigned int x = __builtin_bit_cast(unsigned int, f);
  unsigned int r = x + 0x7fffu + ((x >> 16) & 1u);
  return (unsigned short)(r >> 16);
}
static __device__ __forceinline__ float sigmoidf(float v) {
  return 1.f / (1.f + __expf(-v));
}

typedef const __attribute__((address_space(1))) unsigned int* gas1_t;
typedef __attribute__((address_space(3))) unsigned int* las3_t;
static __device__ __forceinline__ void async_copy16(const void* g, void* l) {
  __builtin_amdgcn_global_load_lds((gas1_t)g, (las3_t)l, 16, 0, 0);
}

#define VMCNT4 asm volatile("s_waitcnt vmcnt(4)" ::: "memory")
#define VMCNT2 asm volatile("s_waitcnt vmcnt(2)" ::: "memory")
#define VMCNT0 asm volatile("s_waitcnt vmcnt(0)" ::: "memory")
#define LGKM0  asm volatile("s_waitcnt lgkmcnt(0)" ::: "memory")
#define SBAR   __builtin_amdgcn_s_barrier()
#define SCHED0 __builtin_amdgcn_sched_barrier(0)

// ---------------- fp32 -> bf16 convert (x8 vectorized) ----------------
__global__ void cvt_f32_bf16(const float* __restrict__ in,
                             unsigned short* __restrict__ out, long n8) {
  long i = (long)blockIdx.x * blockDim.x + threadIdx.x;
  long stride = (long)gridDim.x * blockDim.x;
  for (; i < n8; i += stride) {
    const float4* p = (const float4*)(in + i * 8);
    float4 a = p[0], b = p[1];
    ushort8 o;
    o[0] = f2bf(a.x); o[1] = f2bf(a.y); o[2] = f2bf(a.z); o[3] = f2bf(a.w);
    o[4] = f2bf(b.x); o[5] = f2bf(b.y); o[6] = f2bf(b.z); o[7] = f2bf(b.w);
    *(ushort8*)(out + i * 8) = o;
  }
}

// merged weight converts: W_in (2M elems), W_dt (1M), W_out (1M); idx in x8 units
__global__ void cvt_w3(const float* __restrict__ w1, unsigned short* __restrict__ o1,
                       const float* __restrict__ w2, unsigned short* __restrict__ o2,
                       const float* __restrict__ w3, unsigned short* __restrict__ o3) {
  long i = (long)blockIdx.x * blockDim.x + threadIdx.x;   // 0..524287
  const float* src; unsigned short* dst; long off;
  if (i < 262144)      { src = w1; dst = o1; off = i; }
  else if (i < 393216) { src = w2; dst = o2; off = i - 262144; }
  else                 { src = w3; dst = o3; off = i - 393216; }
  const float4* p = (const float4*)(src + off * 8);
  float4 a = p[0], b = p[1];
  ushort8 o;
  o[0] = f2bf(a.x); o[1] = f2bf(a.y); o[2] = f2bf(a.z); o[3] = f2bf(a.w);
  o[4] = f2bf(b.x); o[5] = f2bf(b.y); o[6] = f2bf(b.z); o[7] = f2bf(b.w);
  *(ushort8*)(dst + off * 8) = o;
}

// ---------------- 256x256 snake-phase bf16 GEMM: C = A[M,K] * Bw[N,K]^T + bias ----
// KT=16 K-tiles of BK=64. 8 waves (2M x 4N), per-wave out 128x64. LDS 128 KB dbuf.
// Snake phases: P0=(0,0) reads af0+bf0; P1=(1,0) reads af1 (bf0 held);
//   P2=(1,1) reads bf1 (af1 held); P3=(0,1) re-reads af0 (bf1 held).
// 32 ds_read_b128/wave/K-tile (vs 48 quadrant) -> LDS path 2860clk vs MFMA 2482.
// Issue order per tile t->t+1: P0:A0, P1:B0, P2:A1, P3:B1 (2 gload_lds each).
// Counted waits: end-P0 vmcnt(4) [A1(t) done], end-P1 vmcnt(4) [B1(t)],
//   end-P2 none, end-P3 vmcnt(4) [A0,B0(t+1)]. Tail: vmcnt(2), vmcnt(0).
// EPI 0: +bias->bf16 ; 1: sigmoid(+bias)->bf16 ; 2: +bias->fp32. Epilogue staged
// through per-wave 16KB LDS region (XOR-swizzled) for coalesced global stores.
template<int EPI>
__global__ __launch_bounds__(512, 2) void gemm256(
    const unsigned short* __restrict__ A, long lda,
    const unsigned short* __restrict__ Bw,
    const float* __restrict__ bias,
    void* __restrict__ Cout, long ldc,
    int nbx)
{
  constexpr int KT = 16;
  __shared__ __align__(16) unsigned short lds[65536];  // 128 KiB

  const int tid = threadIdx.x;
  const int l  = tid & 63, w = tid >> 6;
  const int wm = w >> 2, wn = w & 3;
  const int fr = l & 15, g = l >> 4;
  const int t8 = tid >> 3;
  const int c8x = ((l & 7) ^ (l >> 3)) << 4;     // staging source XOR (bytes)
  const int s0 = ((g ^ (fr & 7)) << 4);          // ds_read swizzle, kk=0
  const int s1 = s0 ^ 0x40;                      // kk=1
  const int tB = (w >> 2) * 64 + (w & 3) * 8 + (l >> 3);

  const int nwg = gridDim.x;
  const int cpx = nwg >> 3;
  const int bid = blockIdx.x;
  const int swz = (bid & 7) * cpx + (bid >> 3);
  const long m0 = (long)(swz / nbx) * 256;
  const long n0 = (long)(swz % nbx) * 256;

  const char* Ab = (const char*)A;
  const char* Bb = (const char*)Bw;
  const long ldab = lda * 2;
  char* LB = (char*)lds;

  auto stA = [&](int kt, int h, int nb) {
    char* lb = LB + nb * 32768 + h * 16384 + w * 1024;
    long col = (long)kt * 128 + c8x;
    async_copy16(Ab + (m0 + h * 64 + t8) * ldab + col, lb);
    async_copy16(Ab + (m0 + 128 + h * 64 + t8) * ldab + col, lb + 8192);
  };
  auto stB = [&](int kt, int h, int nb) {
    char* lb = LB + 65536 + nb * 32768 + h * 16384 + w * 1024;
    long col = (long)kt * 128 + c8x;
    async_copy16(Bb + (n0 + tB + h * 32) * 2048 + col, lb);
    async_copy16(Bb + (n0 + tB + 128 + h * 32) * 2048 + col, lb + 8192);
  };

  f32x4 acc[8][4] = {};

  // prologue: tile 0 in steady-state order A0,B0,A1,B1
  stA(0, 0, 0); stB(0, 0, 0); stA(0, 1, 0); stB(0, 1, 0);
  VMCNT4; SCHED0; SBAR;

#define RD_A(DST, MH) do {                                                     \
    const char* p0_ = LB + cur * 32768 + (MH) * 16384 + wm * 8192 + fr * 128 + s0; \
    const char* p1_ = LB + cur * 32768 + (MH) * 16384 + wm * 8192 + fr * 128 + s1; \
    _Pragma("unroll") for (int mi = 0; mi < 4; ++mi) {                         \
      DST[mi][0] = *(const short8*)(p0_ + mi * 2048);                          \
      DST[mi][1] = *(const short8*)(p1_ + mi * 2048); }                        \
  } while (0)
#define RD_B(DST, NH) do {                                                     \
    const char* p0_ = LB + 65536 + cur * 32768 + (NH) * 16384 + wn * 4096 + fr * 128 + s0; \
    const char* p1_ = LB + 65536 + cur * 32768 + (NH) * 16384 + wn * 4096 + fr * 128 + s1; \
    _Pragma("unroll") for (int ni = 0; ni < 2; ++ni) {                         \
      DST[ni][0] = *(const short8*)(p0_ + ni * 2048);                          \
      DST[ni][1] = *(const short8*)(p1_ + ni * 2048); }                        \
  } while (0)
#define MM(AF, BF, MB, NB) do {                                                \
    __builtin_amdgcn_s_setprio(1);                                             \
    _Pragma("unroll") for (int mi = 0; mi < 4; ++mi)                           \
    _Pragma("unroll") for (int ni = 0; ni < 2; ++ni) {                         \
      acc[(MB)+mi][(NB)+ni] = __builtin_amdgcn_mfma_f32_16x16x32_bf16(         \
          AF[mi][0], BF[ni][0], acc[(MB)+mi][(NB)+ni], 0, 0, 0);               \
      acc[(MB)+mi][(NB)+ni] = __builtin_amdgcn_mfma_f32_16x16x32_bf16(         \
          AF[mi][1], BF[ni][1], acc[(MB)+mi][(NB)+ni], 0, 0, 0); }             \
    __builtin_amdgcn_s_setprio(0);                                             \
  } while (0)

  for (int t = 0; t < KT; ++t) {
    const int cur = t & 1, nxt = cur ^ 1;
    const bool notlast = (t + 1 < KT);
    short8 af0[4][2], af1[4][2], bf0[2][2], bf1[2][2];
    // P0: (mh0,nh0)
    RD_A(af0, 0); RD_B(bf0, 0);
    if (notlast) stA(t + 1, 0, nxt);
    SCHED0; SBAR;
    MM(af0, bf0, 0, 0);
    if (notlast) { VMCNT4; } else { VMCNT2; }
    SCHED0; SBAR; SCHED0;
    // P1: (mh1,nh0)
    RD_A(af1, 1);
    if (notlast) stB(t + 1, 0, nxt);
    SCHED0; SBAR;
    MM(af1, bf0, 4, 0);
    if (notlast) { VMCNT4; } else { VMCNT0; }
    SCHED0; SBAR; SCHED0;
    // P2: (mh1,nh1)
    RD_B(bf1, 1);
    if (notlast) stA(t + 1, 1, nxt);
    SCHED0; SBAR;
    MM(af1, bf1, 4, 2);
    SCHED0; SBAR; SCHED0;
    // P3: (mh0,nh1) — re-read af0 (resident data, no vm wait needed)
    RD_A(af0, 0);
    if (notlast) stB(t + 1, 1, nxt);
    SCHED0; SBAR;
    MM(af0, bf1, 0, 2);
    if (notlast) { VMCNT4; }
    SCHED0; SBAR; SCHED0;
  }
#undef RD_A
#undef RD_B
#undef MM

  __syncthreads();   // all LDS fragment reads done; reuse LDS for epilogue

  // ---- epilogue via per-wave 16KB LDS reshape -> coalesced stores ----
  char* ep = LB + w * 16384;
  const int rq = l >> 4;
  if (EPI != 2) {
    // stage bf16 [128 rows][64 cols], byte = row*128 + col*2, ^((row&7)<<4)
#pragma unroll
    for (int mi = 0; mi < 8; ++mi)
#pragma unroll
      for (int ni = 0; ni < 4; ++ni) {
        int cl = ni * 16 + fr;
        float bv = bias[n0 + wn * 64 + cl];
#pragma unroll
        for (int r = 0; r < 4; ++r) {
          float v = acc[mi][ni][r] + bv;
          if (EPI == 1) v = sigmoidf(v);
          int row = mi * 16 + rq * 4 + r;
          int byte = (row * 128 + cl * 2) ^ ((row & 7) << 4);
          *(unsigned short*)(ep + byte) = f2bf(v);
        }
      }
    LGKM0; SCHED0;
#pragma unroll
    for (int i = 0; i < 16; ++i) {
      int row = i * 8 + (l >> 3);
      int cb = (l & 7) * 16;
      int byte = (row * 128 + cb) ^ ((row & 7) << 4);
      short8 v = *(const short8*)(ep + byte);
      *(short8*)((unsigned short*)Cout + (m0 + wm * 128 + row) * ldc
                 + n0 + wn * 64 + (cb >> 1)) = v;
    }
  } else {
    // fp32: two passes of 64 rows, [64 rows][64 cols] f32, byte=row*256+col*4
#pragma unroll
    for (int p = 0; p < 2; ++p) {
#pragma unroll
      for (int mi = 0; mi < 4; ++mi)
#pragma unroll
        for (int ni = 0; ni < 4; ++ni) {
          int cl = ni * 16 + fr;
          float bv = bias[n0 + wn * 64 + cl];
#pragma unroll
          for (int r = 0; r < 4; ++r) {
            float v = acc[p * 4 + mi][ni][r] + bv;
            int row = mi * 16 + rq * 4 + r;   // 0..63
            int byte = (row * 256 + cl * 4) ^ ((row & 7) << 4);
            *(float*)(ep + byte) = v;
          }
        }
      LGKM0; SCHED0;
#pragma unroll
      for (int i = 0; i < 16; ++i) {
        int row = i * 4 + (l >> 4);
        int cb = (l & 15) * 16;
        int byte = (row * 256 + cb) ^ ((row & 7) << 4);
        f32x4 v = *(const f32x4*)(ep + byte);
        *(f32x4*)((float*)Cout + (m0 + wm * 128 + p * 64 + row) * ldc
                  + n0 + wn * 64 + (cb >> 2)) = v;
      }
      LGKM0; SCHED0;   // pass-1 reads drained before pass-2 overwrites
    }
  }
}

// ---------------- scan pass A: per-chunk decay product + local h ----------------
__global__ void scan_passA(const unsigned short* __restrict__ dtb,   // [M,D] bf16
                           const unsigned short* __restrict__ xz,    // [M,2D] bf16
                           float* __restrict__ P, float* __restrict__ Hl)
{
  int idx = blockIdx.x * blockDim.x + threadIdx.x;   // 0 .. 65535
  int d8 = idx & 127;
  int c  = (idx >> 7) & 31;
  int b  = idx >> 12;
  int d0 = d8 * 8;
  long mbase = (long)b * T_ + (long)c * CL;
  float h[8] = {0,0,0,0,0,0,0,0};
  float p[8] = {1,1,1,1,1,1,1,1};
  for (int t = 0; t < CL; ++t) {
    long m = mbase + t;
    ushort8 dv = *(const ushort8*)(dtb + m * D_ + d0);
    ushort8 xv = *(const ushort8*)(xz + m * (2 * D_) + d0);
#pragma unroll
    for (int j = 0; j < 8; ++j) {
      float dt = bf2f(dv[j]);
      float xp = bf2f(xv[j]);
      float om = 1.f - dt;
      h[j] = om * h[j] + dt * xp;
      p[j] *= om;
    }
  }
  long pb = ((long)(b * NC + c)) * D_ + d0;
#pragma unroll
  for (int j = 0; j < 8; ++j) { P[pb + j] = p[j]; Hl[pb + j] = h[j]; }
}

// ---------------- scan pass C: fold chunk summaries + replay, fuse sigmoid(gate) ----
__global__ void scan_passC(unsigned short* dts,                      // in: dt, out: s
                           const unsigned short* __restrict__ xz,    // [M,2D]
                           const float* __restrict__ h0,             // [B,D]
                           const float* __restrict__ P,
                           const float* __restrict__ Hl)
{
  int idx = blockIdx.x * blockDim.x + threadIdx.x;
  int d8 = idx & 127;
  int c  = (idx >> 7) & 31;
  int b  = idx >> 12;
  int d0 = d8 * 8;
  long mbase = (long)b * T_ + (long)c * CL;

  float h[8];
#pragma unroll
  for (int j = 0; j < 8; ++j) h[j] = h0[(long)b * D_ + d0 + j];

  for (int jc = 0; jc < c; ++jc) {
    long pb = ((long)(b * NC + jc)) * D_ + d0;
    float pj[8], hj[8];
    *(f32x4*)&pj[0] = *(const f32x4*)(P + pb);
    *(f32x4*)&pj[4] = *(const f32x4*)(P + pb + 4);
    *(f32x4*)&hj[0] = *(const f32x4*)(Hl + pb);
    *(f32x4*)&hj[4] = *(const f32x4*)(Hl + pb + 4);
#pragma unroll
    for (int j = 0; j < 8; ++j) h[j] = hj[j] + pj[j] * h[j];
  }

  for (int t = 0; t < CL; ++t) {
    long m = mbase + t;
    ushort8 dv = *(const ushort8*)(dts + m * D_ + d0);
    ushort8 xv = *(const ushort8*)(xz + m * (2 * D_) + d0);
    ushort8 gv = *(const ushort8*)(xz + m * (2 * D_) + D_ + d0);
    ushort8 ov;
#pragma unroll
    for (int j = 0; j < 8; ++j) {
      float dt = bf2f(dv[j]);
      float xp = bf2f(xv[j]);
      h[j] = (1.f - dt) * h[j] + dt * xp;
      float gt = bf2f(gv[j]);
      ov[j] = f2bf(h[j] * sigmoidf(gt));
    }
    *(ushort8*)(dts + m * D_ + d0) = ov;
  }
}

// ---------------- launch ----------------
extern "C" void kernel_launch(void* const* d_in, const int* in_sizes, int n_in,
                              void* d_out, int out_size, void* d_ws, size_t ws_size,
                              hipStream_t stream) {
  const float* x     = (const float*)d_in[0];
  const float* h0    = (const float*)d_in[1];
  const float* W_in  = (const float*)d_in[2];
  const float* b_in  = (const float*)d_in[3];
  const float* W_dt  = (const float*)d_in[4];
  const float* b_dt  = (const float*)d_in[5];
  const float* W_out = (const float*)d_in[6];
  const float* b_out = (const float*)d_in[7];
  float* out = (float*)d_out;

  char* ws = (char*)d_ws;
  const size_t OFF_XB    = 0;                     // x bf16        [M,D]    64 MiB
  const size_t OFF_WIN   = 67108864;              // W_in bf16     [2D,D]    4 MiB
  const size_t OFF_WDT   = 71303168;              // W_dt bf16     [D,D]     2 MiB
  const size_t OFF_WOUT  = 73400320;              // W_out bf16    [D,D]     2 MiB
  const size_t OFF_XZ    = 75497472;              // xz bf16       [M,2D]  128 MiB
  const size_t OFF_DTS   = 209715200;             // dt/s bf16     [M,D]    64 MiB
  const size_t OFF_P     = 276824064;             // P fp32        [B,NC,D]  2 MiB
  const size_t OFF_HL    = 278921216;             // Hl fp32       [B,NC,D]  2 MiB
  const size_t NEEDED    = 281018368;
  if (ws_size < NEEDED) return;

  unsigned short* xb    = (unsigned short*)(ws + OFF_XB);
  unsigned short* wbin  = (unsigned short*)(ws + OFF_WIN);
  unsigned short* wbdt  = (unsigned short*)(ws + OFF_WDT);
  unsigned short* wbout = (unsigned short*)(ws + OFF_WOUT);
  unsigned short* xz    = (unsigned short*)(ws + OFF_XZ);
  unsigned short* dts   = (unsigned short*)(ws + OFF_DTS);
  float* P  = (float*)(ws + OFF_P);
  float* Hl = (float*)(ws + OFF_HL);

  cvt_f32_bf16<<<2048, 256, 0, stream>>>(x, xb, (long)M_ * D_ / 8);
  cvt_w3<<<2048, 256, 0, stream>>>(W_in, wbin, W_dt, wbdt, W_out, wbout);

  // xz = x @ W_in^T + b_in            (bf16 out, [M, 2D])
  gemm256<0><<<(M_/256)*(2*D_/256), 512, 0, stream>>>(xb, D_, wbin, b_in, xz, 2*D_, 2*D_/256);
  // dt = sigmoid(x_part @ W_dt^T + b_dt)   (bf16 out, [M, D]); x_part = xz[:, :D]
  gemm256<1><<<(M_/256)*(D_/256), 512, 0, stream>>>(xz, 2*D_, wbdt, b_dt, dts, D_, D_/256);
  // chunked scan
  scan_passA<<<256, 256, 0, stream>>>(dts, xz, P, Hl);
  scan_passC<<<256, 256, 0, stream>>>(dts, xz, h0, P, Hl);
  // y = s @ W_out^T + b_out           (fp32 out)
  gemm256<2><<<(M_/256)*(D_/256), 512, 0, stream>>>(dts, D_, wbout, b_out, out, D_, D_/256);
}